// Round 1
// baseline (556.558 us; speedup 1.0000x reference)
//
#include <hip/hip_runtime.h>

#define B 256
#define D 128
#define NEG 1024
#define SAMPLES 300000
#define TEMP 0.07f
#define EPS 1e-12f

// inverted-index geometry for the fused copy+score kernel
#define ROWS_PER_BLK 32
#define NBUCKETS (SAMPLES / ROWS_PER_BLK)   // 9375 (exact: 9375*32 = 300000)
#define CAP 96                              // Poisson(28); P(overflow) ~ e^-50 per bucket

// output layout: scores [4,B,1+NEG] | audio_memory_new [SAMPLES,D] | video_memory_new [SAMPLES,D]
constexpr int SCORES_ELEMS = 4 * B * (NEG + 1);            // 1,049,600
constexpr int MEM_ELEMS    = SAMPLES * D;                   // 38,400,000

__device__ inline float wave_reduce_sum(float x) {
    #pragma unroll
    for (int off = 32; off > 0; off >>= 1) x += __shfl_xor(x, off, 64);
    return x;
}

// One wave per batch row: normalize embeddings, positive scores, momentum rows.
__global__ __launch_bounds__(64) void prep_kernel(
    const float* __restrict__ audio_emb, const float* __restrict__ video_emb,
    const float* __restrict__ a_mem, const float* __restrict__ v_mem,
    const int* __restrict__ indices,
    float* __restrict__ na, float* __restrict__ nv,
    float* __restrict__ new_a, float* __restrict__ new_v,
    float* __restrict__ scores)
{
    const int b = blockIdx.x;
    const int l = threadIdx.x;  // lane handles elements [2l, 2l+1]

    float2 a = ((const float2*)(audio_emb + b * D))[l];
    float2 v = ((const float2*)(video_emb + b * D))[l];

    float sa = wave_reduce_sum(a.x * a.x + a.y * a.y);
    float sv = wave_reduce_sum(v.x * v.x + v.y * v.y);
    float ira = 1.0f / fmaxf(sqrtf(sa), EPS);
    float irv = 1.0f / fmaxf(sqrtf(sv), EPS);
    float2 naf = {a.x * ira, a.y * ira};
    float2 nvf = {v.x * irv, v.y * irv};
    ((float2*)(na + b * D))[l] = naf;
    ((float2*)(nv + b * D))[l] = nvf;

    const long long idx = (long long)indices[b];
    float2 pa = ((const float2*)(a_mem + idx * D))[l];
    float2 pv = ((const float2*)(v_mem + idx * D))[l];

    // positive scores: order = [pos_v·na, pos_a·nv, pos_a·na, pos_v·nv]
    float d0 = wave_reduce_sum(pv.x * naf.x + pv.y * naf.y);
    float d1 = wave_reduce_sum(pa.x * nvf.x + pa.y * nvf.y);
    float d2 = wave_reduce_sum(pa.x * naf.x + pa.y * naf.y);
    float d3 = wave_reduce_sum(pv.x * nvf.x + pv.y * nvf.y);
    if (l == 0) {
        scores[(0 * B + b) * (NEG + 1)] = d0 / TEMP;
        scores[(1 * B + b) * (NEG + 1)] = d1 / TEMP;
        scores[(2 * B + b) * (NEG + 1)] = d2 / TEMP;
        scores[(3 * B + b) * (NEG + 1)] = d3 / TEMP;
    }

    // momentum update rows (normalized)
    float2 ta = {0.5f * (pa.x + naf.x), 0.5f * (pa.y + naf.y)};
    float2 tv = {0.5f * (pv.x + nvf.x), 0.5f * (pv.y + nvf.y)};
    float sta = wave_reduce_sum(ta.x * ta.x + ta.y * ta.y);
    float stv = wave_reduce_sum(tv.x * tv.x + tv.y * tv.y);
    float irta = 1.0f / fmaxf(sqrtf(sta), EPS);
    float irtv = 1.0f / fmaxf(sqrtf(stv), EPS);
    ta.x *= irta; ta.y *= irta;
    tv.x *= irtv; tv.y *= irtv;
    ((float2*)(new_a + b * D))[l] = ta;
    ((float2*)(new_v + b * D))[l] = tv;
}

// ---------------- inverted-index build ----------------

__global__ __launch_bounds__(256) void zero_cnt_kernel(int* __restrict__ cnt) {
    int i = blockIdx.x * blockDim.x + threadIdx.x;
    if (i < NBUCKETS) cnt[i] = 0;
}

// One thread per (b,n): compute shifted negative row, bucket it.
__global__ __launch_bounds__(256) void fill_entries_kernel(
    const int* __restrict__ indices, const int* __restrict__ neg_samples,
    int* __restrict__ cnt, unsigned int* __restrict__ entries)
{
    int i = blockIdx.x * blockDim.x + threadIdx.x;   // over B*NEG
    if (i >= B * NEG) return;
    const int b = i >> 10;          // NEG = 1024
    const int n = i & (NEG - 1);
    const int pos = indices[b];
    const int ns  = neg_samples[i];
    const int ni  = ns + (ns >= pos ? 1 : 0);        // skip positive
    const int bucket = ni >> 5;                       // ROWS_PER_BLK = 32
    const int r      = ni & 31;
    const int slot = atomicAdd(&cnt[bucket], 1);
    if (slot < CAP)
        entries[bucket * CAP + slot] =
            (unsigned)b | ((unsigned)n << 8) | ((unsigned)r << 18);
}

// ---------------- fused copy + negative scoring ----------------
// Each block owns 32 consecutive rows of BOTH banks: streams them
// global->LDS + global->out (the mandatory copy), then computes every
// negative dot whose row lands in this chunk from LDS. The 268 MB random
// gather of the old neg kernel is eliminated.
__global__ __launch_bounds__(256) void fused_copy_score_kernel(
    const float* __restrict__ a_mem, const float* __restrict__ v_mem,
    const float* __restrict__ na, const float* __restrict__ nv,
    const int* __restrict__ cnt, const unsigned int* __restrict__ entries,
    float* __restrict__ out_a, float* __restrict__ out_v,
    float* __restrict__ scores)
{
    __shared__ float lds_a[ROWS_PER_BLK][D];   // 16 KB
    __shared__ float lds_v[ROWS_PER_BLK][D];   // 16 KB -> 5 blocks/CU

    const int k = blockIdx.x;
    const int t = threadIdx.x;
    const long long base = (long long)k * ROWS_PER_BLK * D;

    const float4* ga = (const float4*)(a_mem + base);
    const float4* gv = (const float4*)(v_mem + base);
    float4* oa = (float4*)(out_a + base);
    float4* ov = (float4*)(out_v + base);
    float4* la = (float4*)&lds_a[0][0];
    float4* lv = (float4*)&lds_v[0][0];

    #pragma unroll
    for (int j = 0; j < 4; ++j) {              // 1024 float4 per bank / 256 thr
        const int i = j * 256 + t;
        float4 x = ga[i]; oa[i] = x; la[i] = x;
        float4 y = gv[i]; ov[i] = y; lv[i] = y;
    }
    __syncthreads();

    const int ne = min(cnt[k], CAP);
    const int w = t >> 6, lane = t & 63;       // 4 waves; one entry per wave
    for (int e = w; e < ne; e += 4) {
        const unsigned int ent = entries[k * CAP + e];
        const int b = ent & 255;
        const int n = (ent >> 8) & (NEG - 1);
        const int r = ent >> 18;

        float2 A  = ((const float2*)&lds_a[r][0])[lane];
        float2 V  = ((const float2*)&lds_v[r][0])[lane];
        float2 NA = ((const float2*)(na + b * D))[lane];   // L1/L2-resident (256 KB total)
        float2 NV = ((const float2*)(nv + b * D))[lane];

        float s0 = V.x * NA.x + V.y * NA.y;   // neg_v · na
        float s1 = A.x * NV.x + A.y * NV.y;   // neg_a · nv
        float s2 = A.x * NA.x + A.y * NA.y;   // neg_a · na
        float s3 = V.x * NV.x + V.y * NV.y;   // neg_v · nv

        #pragma unroll
        for (int off = 32; off > 0; off >>= 1) {
            s0 += __shfl_xor(s0, off, 64);
            s1 += __shfl_xor(s1, off, 64);
            s2 += __shfl_xor(s2, off, 64);
            s3 += __shfl_xor(s3, off, 64);
        }
        if (lane == 0) {
            scores[(0 * B + b) * (NEG + 1) + 1 + n] = s0 / TEMP;
            scores[(1 * B + b) * (NEG + 1) + 1 + n] = s1 / TEMP;
            scores[(2 * B + b) * (NEG + 1) + 1 + n] = s2 / TEMP;
            scores[(3 * B + b) * (NEG + 1) + 1 + n] = s3 / TEMP;
        }
    }
}

// ---------------- fallback path (previous verified kernels) ----------------

__global__ __launch_bounds__(256) void neg_scores_kernel(
    const float* __restrict__ a_mem, const float* __restrict__ v_mem,
    const int* __restrict__ indices, const int* __restrict__ neg_samples,
    const float* __restrict__ na, const float* __restrict__ nv,
    float* __restrict__ scores)
{
    const int b    = blockIdx.y;
    const int hw   = threadIdx.x >> 5;
    const int lane = threadIdx.x & 31;
    const int n    = blockIdx.x * 8 + hw;

    const int pos = indices[b];
    const int ns  = neg_samples[b * NEG + n];
    const long long ni = (long long)ns + (ns >= pos ? 1 : 0);

    float4 A  = ((const float4*)(a_mem + ni * D))[lane];
    float4 V  = ((const float4*)(v_mem + ni * D))[lane];
    float4 NA = ((const float4*)(na + (long long)b * D))[lane];
    float4 NV = ((const float4*)(nv + (long long)b * D))[lane];

    float s0 = V.x * NA.x + V.y * NA.y + V.z * NA.z + V.w * NA.w;
    float s1 = A.x * NV.x + A.y * NV.y + A.z * NV.z + A.w * NV.w;
    float s2 = A.x * NA.x + A.y * NA.y + A.z * NA.z + A.w * NA.w;
    float s3 = V.x * NV.x + V.y * NV.y + V.z * NV.z + V.w * NV.w;

    #pragma unroll
    for (int off = 16; off > 0; off >>= 1) {
        s0 += __shfl_xor(s0, off, 64);
        s1 += __shfl_xor(s1, off, 64);
        s2 += __shfl_xor(s2, off, 64);
        s3 += __shfl_xor(s3, off, 64);
    }
    if (lane == 0) {
        scores[(0 * B + b) * (NEG + 1) + 1 + n] = s0 / TEMP;
        scores[(1 * B + b) * (NEG + 1) + 1 + n] = s1 / TEMP;
        scores[(2 * B + b) * (NEG + 1) + 1 + n] = s2 / TEMP;
        scores[(3 * B + b) * (NEG + 1) + 1 + n] = s3 / TEMP;
    }
}

__global__ __launch_bounds__(256) void copy_kernel(
    const float4* __restrict__ a_mem, const float4* __restrict__ v_mem,
    float4* __restrict__ out_a, float4* __restrict__ out_v, int n4)
{
    int i = blockIdx.x * blockDim.x + threadIdx.x;
    if (i < n4) {
        out_a[i] = a_mem[i];
    } else {
        i -= n4;
        if (i < n4) out_v[i] = v_mem[i];
    }
}

// Scatter updated rows; last occurrence wins on duplicate indices.
__global__ __launch_bounds__(128) void scatter_kernel(
    const int* __restrict__ indices,
    const float* __restrict__ new_a, const float* __restrict__ new_v,
    float* __restrict__ out_a, float* __restrict__ out_v)
{
    const int b = blockIdx.x;
    const int t = threadIdx.x;  // D threads
    const int myidx = indices[b];

    __shared__ int skip;
    if (t == 0) skip = 0;
    __syncthreads();
    for (int b2 = b + 1 + t; b2 < B; b2 += blockDim.x)
        if (indices[b2] == myidx) skip = 1;  // benign race: only ever set to 1
    __syncthreads();
    if (skip) return;

    out_a[(long long)myidx * D + t] = new_a[b * D + t];
    out_v[(long long)myidx * D + t] = new_v[b * D + t];
}

extern "C" void kernel_launch(void* const* d_in, const int* in_sizes, int n_in,
                              void* d_out, int out_size, void* d_ws, size_t ws_size,
                              hipStream_t stream) {
    const float* audio_emb   = (const float*)d_in[0];
    const float* video_emb   = (const float*)d_in[1];
    const float* a_mem       = (const float*)d_in[2];
    const float* v_mem       = (const float*)d_in[3];
    const int*   indices     = (const int*)d_in[4];
    const int*   neg_samples = (const int*)d_in[5];

    float* out    = (float*)d_out;
    float* scores = out;
    float* out_a  = out + SCORES_ELEMS;
    float* out_v  = out_a + MEM_ELEMS;

    float* ws    = (float*)d_ws;
    float* na    = ws;
    float* nv    = na + B * D;
    float* new_a = nv + B * D;
    float* new_v = new_a + B * D;
    int*          cnt     = (int*)(new_v + B * D);
    unsigned int* entries = (unsigned int*)(cnt + NBUCKETS);

    const size_t ws_needed = (size_t)(4 * B * D) * sizeof(float)
                           + (size_t)NBUCKETS * sizeof(int)
                           + (size_t)NBUCKETS * CAP * sizeof(unsigned int);

    prep_kernel<<<B, 64, 0, stream>>>(audio_emb, video_emb, a_mem, v_mem, indices,
                                      na, nv, new_a, new_v, scores);

    if (ws_size >= ws_needed) {
        // fused path: build inverted index, then single bank-streaming pass
        zero_cnt_kernel<<<(NBUCKETS + 255) / 256, 256, 0, stream>>>(cnt);
        fill_entries_kernel<<<(B * NEG) / 256, 256, 0, stream>>>(indices, neg_samples,
                                                                 cnt, entries);
        fused_copy_score_kernel<<<NBUCKETS, 256, 0, stream>>>(a_mem, v_mem, na, nv,
                                                              cnt, entries,
                                                              out_a, out_v, scores);
    } else {
        // fallback: previous verified 4-kernel path
        dim3 g2(NEG / 8, B);
        neg_scores_kernel<<<g2, 256, 0, stream>>>(a_mem, v_mem, indices, neg_samples,
                                                  na, nv, scores);
        const int n4 = MEM_ELEMS / 4;
        copy_kernel<<<(2 * n4) / 256, 256, 0, stream>>>((const float4*)a_mem,
                                                        (const float4*)v_mem,
                                                        (float4*)out_a, (float4*)out_v, n4);
    }

    scatter_kernel<<<B, D, 0, stream>>>(indices, new_a, new_v, out_a, out_v);
}